// Round 13
// baseline (296.304 us; speedup 1.0000x reference)
//
#include <hip/hip_runtime.h>

#define N_NODES 50000
#define N_EDGES 800000
#define D 64
#define NSLICE 8
#define SLICE_N ((N_NODES + NSLICE - 1) / NSLICE)   // 6250
#define BCAP 64        // bucket capacity; deg ~ Poisson(16), P(deg>=64) ~ 1e-19

// float -> bf16 (round-to-nearest-even), as raw ushort
__device__ __forceinline__ unsigned short f2bf(float f) {
    unsigned int u = __builtin_bit_cast(unsigned int, f);
    u += 0x7fffu + ((u >> 16) & 1u);
    return (unsigned short)(u >> 16);
}
__device__ __forceinline__ float bflo(unsigned int u) {
    return __builtin_bit_cast(float, u << 16);
}
__device__ __forceinline__ float bfhi(unsigned int u) {
    return __builtin_bit_cast(float, u & 0xffff0000u);
}

// ---------------- shared transform body: yS = h@Ws + b (fp32), yN = h@Wn (bf16) ----
__device__ __forceinline__ void xform_body(const float* __restrict__ h,
        const float* __restrict__ Ws, const float* __restrict__ Wn,
        const float* __restrict__ b,
        float* __restrict__ yS, unsigned short* __restrict__ yN,
        int gwave, int nwaves, int lane) {
    int mat = gwave & 1;
    const float* W = mat ? Wn : Ws;

    float w[D];
#pragma unroll
    for (int k = 0; k < D; ++k) w[k] = W[k * D + lane];
    float bj = mat ? 0.f : b[lane];

    const int ngroups = (N_NODES + 3) / 4;   // 12500, exact
    for (int g = gwave >> 1; g < ngroups; g += (nwaves >> 1)) {
        const float* x0 = h + (size_t)(g * 4) * D;
        float a0 = bj, a1 = bj, a2 = bj, a3 = bj;
#pragma unroll
        for (int kq = 0; kq < 16; ++kq) {
            float4 v0 = *(const float4*)(x0 + 0 * D + kq * 4);
            float4 v1 = *(const float4*)(x0 + 1 * D + kq * 4);
            float4 v2 = *(const float4*)(x0 + 2 * D + kq * 4);
            float4 v3 = *(const float4*)(x0 + 3 * D + kq * 4);
            a0 = fmaf(v0.x, w[kq * 4 + 0], a0);
            a1 = fmaf(v1.x, w[kq * 4 + 0], a1);
            a2 = fmaf(v2.x, w[kq * 4 + 0], a2);
            a3 = fmaf(v3.x, w[kq * 4 + 0], a3);
            a0 = fmaf(v0.y, w[kq * 4 + 1], a0);
            a1 = fmaf(v1.y, w[kq * 4 + 1], a1);
            a2 = fmaf(v2.y, w[kq * 4 + 1], a2);
            a3 = fmaf(v3.y, w[kq * 4 + 1], a3);
            a0 = fmaf(v0.z, w[kq * 4 + 2], a0);
            a1 = fmaf(v1.z, w[kq * 4 + 2], a1);
            a2 = fmaf(v2.z, w[kq * 4 + 2], a2);
            a3 = fmaf(v3.z, w[kq * 4 + 2], a3);
            a0 = fmaf(v0.w, w[kq * 4 + 3], a0);
            a1 = fmaf(v1.w, w[kq * 4 + 3], a1);
            a2 = fmaf(v2.w, w[kq * 4 + 3], a2);
            a3 = fmaf(v3.w, w[kq * 4 + 3], a3);
        }
        size_t base = (size_t)(g * 4) * D + lane;
        if (mat) {
            yN[base + 0 * D] = f2bf(a0);
            yN[base + 1 * D] = f2bf(a1);
            yN[base + 2 * D] = f2bf(a2);
            yN[base + 3 * D] = f2bf(a3);
        } else {
            yS[base + 0 * D] = a0;
            yS[base + 1 * D] = a1;
            yS[base + 2 * D] = a2;
            yS[base + 3 * D] = a3;
        }
    }
}

// ---------------- FUSED stage 1: layer-0 transform (even blocks) ∥ CSR fill (odd) ----
// Fill role uses the PHYSICAL XCD id (s_getreg HW_REG_XCC_ID, verified m09):
// slice = XCC_ID, so each slice's cnt/csr lines are dirtied by exactly one
// XCD's L2 by construction — R12's static (blockIdx>>1)&7 mapping failed
// (WRITE_SIZE 54.6 MB vs ~25 MB legit). Per-slice atomic chunk cursors
// (wave-level grab, lane-0 atomicAdd + shfl) auto-balance whatever block count
// each XCD received; the round-robin sweep over all 8 slices guarantees every
// slice is drained even if XCC_ID were garbage (stealing only at the tail).
__global__ __launch_bounds__(256) void k_pre(const float* __restrict__ x,
        const float* __restrict__ Ws0, const float* __restrict__ Wn0,
        const float* __restrict__ b0,
        float* __restrict__ yS, unsigned short* __restrict__ yN,
        const int* __restrict__ src, const int* __restrict__ dst,
        int* __restrict__ cnt, int* __restrict__ cursors,
        int* __restrict__ csr) {
    int role = blockIdx.x & 1;
    int sub  = blockIdx.x >> 1;          // 0..1023 within the role
    int lane = threadIdx.x & 63;
    if (role == 0) {
        int gwave = __builtin_amdgcn_readfirstlane(sub * 4 + (int)(threadIdx.x >> 6));
        xform_body(x, Ws0, Wn0, b0, yS, yN, gwave, 4096, lane);
    } else {
        unsigned xcc;
        asm volatile("s_getreg_b32 %0, hwreg(HW_REG_XCC_ID)" : "=s"(xcc));
        for (int t = 0; t < NSLICE; ++t) {
            int slice = (int)((xcc + (unsigned)t) & (NSLICE - 1));
            int lo = slice * SLICE_N, hi = lo + SLICE_N;
            int* cur = cursors + slice * 16;     // 64 B apart: no cursor line sharing
            while (true) {
                int t0 = 0;
                if (lane == 0) t0 = atomicAdd(cur, 512);
                int base = __shfl(t0, 0, 64);    // wave-uniform chunk base
                if (base >= N_EDGES) break;
#pragma unroll
                for (int k = 0; k < 8; ++k) {
                    int e = base + k * 64 + lane;
                    if (e < N_EDGES) {
                        int d = dst[e];
                        if (d >= lo && d < hi) {
                            int p = atomicAdd(&cnt[d], 1);
                            csr[(d << 6) + p] = src[e];
                        }
                    }
                }
            }
        }
    }
}

// ---------------- layer-1 transform (standalone, R10 body) ----------------
__global__ __launch_bounds__(256, 4) void k_xform(const float* __restrict__ h,
        const float* __restrict__ Ws, const float* __restrict__ Wn,
        const float* __restrict__ b,
        float* __restrict__ yS, unsigned short* __restrict__ yN) {
    int lane = threadIdx.x & 63;
    int gwave = __builtin_amdgcn_readfirstlane((blockIdx.x * blockDim.x + threadIdx.x) >> 6);
    int nwaves = (gridDim.x * blockDim.x) >> 6;
    xform_body(h, Ws, Wn, b, yS, yN, gwave, nwaves, lane);
}

// ---------------- fused mean-aggregate + self + epilogue (R10, unchanged) ----------
__global__ __launch_bounds__(256) void k_aggf(const char* __restrict__ yN,
        const float* __restrict__ yS,
        const int* __restrict__ cnt, const int* __restrict__ csr,
        float* __restrict__ out, int relu) {
    int node = __builtin_amdgcn_readfirstlane((blockIdx.x * blockDim.x + threadIdx.x) >> 6);
    int lane = threadIdx.x & 63;
    int q = lane >> 3;          // edge sub-slot 0..7
    int fq = lane & 7;          // uint4 slot within the 128 B row
    int deg = cnt[node];
    const int* bucket = csr + (node << 6);
    unsigned foff = (unsigned)fq * 16u;

    float s0 = 0.f, s1 = 0.f, s2 = 0.f, s3 = 0.f;
    float s4 = 0.f, s5 = 0.f, s6 = 0.f, s7 = 0.f;

#define ROUND16(E0)                                                         \
    {                                                                       \
        int i0 = (E0) + q, i1 = i0 + 8;                                     \
        int b0 = bucket[i0], b1 = bucket[i1];                               \
        unsigned a0 = (i0 < deg) ? ((unsigned)b0 << 7) : 0u;                \
        unsigned a1 = (i1 < deg) ? ((unsigned)b1 << 7) : 0u;                \
        float m0 = (i0 < deg) ? 1.f : 0.f;                                  \
        float m1 = (i1 < deg) ? 1.f : 0.f;                                  \
        uint4 u0 = *(const uint4*)(yN + a0 + foff);                         \
        uint4 u1 = *(const uint4*)(yN + a1 + foff);                         \
        s0 = fmaf(m0, bflo(u0.x), s0); s0 = fmaf(m1, bflo(u1.x), s0);       \
        s1 = fmaf(m0, bfhi(u0.x), s1); s1 = fmaf(m1, bfhi(u1.x), s1);       \
        s2 = fmaf(m0, bflo(u0.y), s2); s2 = fmaf(m1, bflo(u1.y), s2);       \
        s3 = fmaf(m0, bfhi(u0.y), s3); s3 = fmaf(m1, bfhi(u1.y), s3);       \
        s4 = fmaf(m0, bflo(u0.z), s4); s4 = fmaf(m1, bflo(u1.z), s4);       \
        s5 = fmaf(m0, bfhi(u0.z), s5); s5 = fmaf(m1, bfhi(u1.z), s5);       \
        s6 = fmaf(m0, bflo(u0.w), s6); s6 = fmaf(m1, bflo(u1.w), s6);       \
        s7 = fmaf(m0, bfhi(u0.w), s7); s7 = fmaf(m1, bfhi(u1.w), s7);       \
    }

    ROUND16(0)                          // deg<=16: 53% of nodes stop here
    if (deg > 16) ROUND16(16)           // ~44%
    if (deg > 32) {                     // ~3%
        ROUND16(32)
        if (deg > 48) ROUND16(48)       // ~1e-4
    }
#undef ROUND16

    s0 += __shfl_xor(s0, 8, 64); s0 += __shfl_xor(s0, 16, 64); s0 += __shfl_xor(s0, 32, 64);
    s1 += __shfl_xor(s1, 8, 64); s1 += __shfl_xor(s1, 16, 64); s1 += __shfl_xor(s1, 32, 64);
    s2 += __shfl_xor(s2, 8, 64); s2 += __shfl_xor(s2, 16, 64); s2 += __shfl_xor(s2, 32, 64);
    s3 += __shfl_xor(s3, 8, 64); s3 += __shfl_xor(s3, 16, 64); s3 += __shfl_xor(s3, 32, 64);
    s4 += __shfl_xor(s4, 8, 64); s4 += __shfl_xor(s4, 16, 64); s4 += __shfl_xor(s4, 32, 64);
    s5 += __shfl_xor(s5, 8, 64); s5 += __shfl_xor(s5, 16, 64); s5 += __shfl_xor(s5, 32, 64);
    s6 += __shfl_xor(s6, 8, 64); s6 += __shfl_xor(s6, 16, 64); s6 += __shfl_xor(s6, 32, 64);
    s7 += __shfl_xor(s7, 8, 64); s7 += __shfl_xor(s7, 16, 64); s7 += __shfl_xor(s7, 32, 64);

    float sv = (q == 0) ? s0 : (q == 1) ? s1 : (q == 2) ? s2 : (q == 3) ? s3
             : (q == 4) ? s4 : (q == 5) ? s5 : (q == 6) ? s6 : s7;
    int f = fq * 8 + q;                      // feature this lane writes
    float self = yS[(size_t)node * D + f];
    float inv = 1.0f / fmaxf((float)deg, 1.0f);
    float acc = self + sv * inv;
    if (relu) acc = fmaxf(acc, 0.f);
    out[(size_t)node * D + f] = acc;
}

extern "C" void kernel_launch(void* const* d_in, const int* in_sizes, int n_in,
                              void* d_out, int out_size, void* d_ws, size_t ws_size,
                              hipStream_t stream) {
    const float* x   = (const float*)d_in[0];
    const int*   src = (const int*)d_in[1];
    const int*   dst = (const int*)d_in[2];
    const float* Ws0 = (const float*)d_in[3];
    const float* Wn0 = (const float*)d_in[4];
    const float* b0  = (const float*)d_in[5];
    const float* Ws1 = (const float*)d_in[6];
    const float* Wn1 = (const float*)d_in[7];
    const float* b1  = (const float*)d_in[8];
    float* out = (float*)d_out;

    // workspace layout (cnt and cursors adjacent -> one memset)
    char* p = (char*)d_ws;
    float*          yS  = (float*)p;          p += (size_t)N_NODES * D * sizeof(float);
    unsigned short* yN  = (unsigned short*)p; p += (size_t)N_NODES * D * sizeof(unsigned short);
    int* cnt     = (int*)p;                   p += (size_t)N_NODES * sizeof(int);
    int* cursors = (int*)p;                   p += 8 * 16 * sizeof(int);
    int* csr     = (int*)p;                   p += (size_t)N_NODES * BCAP * sizeof(int);

    const int aggBlocks = (N_NODES + 3) / 4;     // 12500: wave per node, exact

    // zero cnt + cursors (contiguous, 200.5 KB)
    hipMemsetAsync(cnt, 0, (size_t)N_NODES * sizeof(int) + 8 * 16 * sizeof(int), stream);

    // stage 1: layer-0 transform ∥ XCD-local CSR fill (co-scheduled)
    k_pre<<<2048, 256, 0, stream>>>(x, Ws0, Wn0, b0, yS, yN, src, dst,
                                    cnt, cursors, csr);

    // layer 0 aggregate -> h in d_out
    k_aggf<<<aggBlocks, 256, 0, stream>>>((const char*)yN, yS, cnt, csr, out, 1);

    // layer 1 transform + aggregate -> d_out
    k_xform<<<1024, 256, 0, stream>>>(out, Ws1, Wn1, b1, yS, yN);
    k_aggf<<<aggBlocks, 256, 0, stream>>>((const char*)yN, yS, cnt, csr, out, 0);
}

// Round 14
// 192.810 us; speedup vs baseline: 1.5368x; 1.5368x over previous
//
#include <hip/hip_runtime.h>

#define N_NODES 50000
#define N_EDGES 800000
#define D 64
#define BCAP 64        // bucket capacity; deg ~ Poisson(16), P(deg>=64) ~ 1e-19

// float -> bf16 (round-to-nearest-even), as raw ushort
__device__ __forceinline__ unsigned short f2bf(float f) {
    unsigned int u = __builtin_bit_cast(unsigned int, f);
    u += 0x7fffu + ((u >> 16) & 1u);
    return (unsigned short)(u >> 16);
}
__device__ __forceinline__ float bflo(unsigned int u) {
    return __builtin_bit_cast(float, u << 16);
}
__device__ __forceinline__ float bfhi(unsigned int u) {
    return __builtin_bit_cast(float, u & 0xffff0000u);
}

// ---------------- shared transform body: yS = h@Ws + b (fp32), yN = h@Wn (bf16) ----
__device__ __forceinline__ void xform_body(const float* __restrict__ h,
        const float* __restrict__ Ws, const float* __restrict__ Wn,
        const float* __restrict__ b,
        float* __restrict__ yS, unsigned short* __restrict__ yN,
        int gwave, int nwaves, int lane) {
    int mat = gwave & 1;
    const float* W = mat ? Wn : Ws;

    float w[D];
#pragma unroll
    for (int k = 0; k < D; ++k) w[k] = W[k * D + lane];
    float bj = mat ? 0.f : b[lane];

    const int ngroups = (N_NODES + 3) / 4;   // 12500, exact
    for (int g = gwave >> 1; g < ngroups; g += (nwaves >> 1)) {
        const float* x0 = h + (size_t)(g * 4) * D;
        float a0 = bj, a1 = bj, a2 = bj, a3 = bj;
#pragma unroll
        for (int kq = 0; kq < 16; ++kq) {
            float4 v0 = *(const float4*)(x0 + 0 * D + kq * 4);
            float4 v1 = *(const float4*)(x0 + 1 * D + kq * 4);
            float4 v2 = *(const float4*)(x0 + 2 * D + kq * 4);
            float4 v3 = *(const float4*)(x0 + 3 * D + kq * 4);
            a0 = fmaf(v0.x, w[kq * 4 + 0], a0);
            a1 = fmaf(v1.x, w[kq * 4 + 0], a1);
            a2 = fmaf(v2.x, w[kq * 4 + 0], a2);
            a3 = fmaf(v3.x, w[kq * 4 + 0], a3);
            a0 = fmaf(v0.y, w[kq * 4 + 1], a0);
            a1 = fmaf(v1.y, w[kq * 4 + 1], a1);
            a2 = fmaf(v2.y, w[kq * 4 + 1], a2);
            a3 = fmaf(v3.y, w[kq * 4 + 1], a3);
            a0 = fmaf(v0.z, w[kq * 4 + 2], a0);
            a1 = fmaf(v1.z, w[kq * 4 + 2], a1);
            a2 = fmaf(v2.z, w[kq * 4 + 2], a2);
            a3 = fmaf(v3.z, w[kq * 4 + 2], a3);
            a0 = fmaf(v0.w, w[kq * 4 + 3], a0);
            a1 = fmaf(v1.w, w[kq * 4 + 3], a1);
            a2 = fmaf(v2.w, w[kq * 4 + 3], a2);
            a3 = fmaf(v3.w, w[kq * 4 + 3], a3);
        }
        size_t base = (size_t)(g * 4) * D + lane;
        if (mat) {
            yN[base + 0 * D] = f2bf(a0);
            yN[base + 1 * D] = f2bf(a1);
            yN[base + 2 * D] = f2bf(a2);
            yN[base + 3 * D] = f2bf(a3);
        } else {
            yS[base + 0 * D] = a0;
            yS[base + 1 * D] = a1;
            yS[base + 2 * D] = a2;
            yS[base + 3 * D] = a3;
        }
    }
}

// ---------------- FUSED stage 1: layer-0 transform (even blocks) ∥ CSR fill (odd) ----
// Fill role is SINGLE-PASS and unsliced: R13's evidence showed the blockIdx%8
// XCD assumption is false here, so the 8-pass dst-slice sweep bought no L2
// locality — only 8x edge re-reads (R12 k_pre FETCH 25.4 MB ~= 8 x 3.2 MB).
// Each fill block owns a contiguous ~782-edge chunk: one dst+src read per
// edge, device-scope atomic cursor, scattered 4 B csr store. The ~30 MB
// line-writeback amplification persists (~5 us of HBM BW) but is cheaper than
// the sweep. cnt is pre-zeroed by a stream-ordered 200 KB memset.
__global__ __launch_bounds__(256) void k_pre(const float* __restrict__ x,
        const float* __restrict__ Ws0, const float* __restrict__ Wn0,
        const float* __restrict__ b0,
        float* __restrict__ yS, unsigned short* __restrict__ yN,
        const int* __restrict__ src, const int* __restrict__ dst,
        int* __restrict__ cnt, int* __restrict__ csr) {
    int role = blockIdx.x & 1;
    int sub  = blockIdx.x >> 1;          // 0..1023 within the role
    if (role == 0) {
        int lane = threadIdx.x & 63;
        int gwave = __builtin_amdgcn_readfirstlane(sub * 4 + (int)(threadIdx.x >> 6));
        xform_body(x, Ws0, Wn0, b0, yS, yN, gwave, 4096, lane);
    } else {
        const int per = (N_EDGES + 1023) / 1024;         // 782
        int e0 = sub * per;
        int e1 = e0 + per; if (e1 > N_EDGES) e1 = N_EDGES;
        for (int e = e0 + (int)threadIdx.x; e < e1; e += 256) {
            int d = dst[e];
            int p = atomicAdd(&cnt[d], 1);
            csr[(d << 6) + p] = src[e];
        }
    }
}

// ---------------- layer-1 transform (standalone, R10 body) ----------------
__global__ __launch_bounds__(256, 4) void k_xform(const float* __restrict__ h,
        const float* __restrict__ Ws, const float* __restrict__ Wn,
        const float* __restrict__ b,
        float* __restrict__ yS, unsigned short* __restrict__ yN) {
    int lane = threadIdx.x & 63;
    int gwave = __builtin_amdgcn_readfirstlane((blockIdx.x * blockDim.x + threadIdx.x) >> 6);
    int nwaves = (gridDim.x * blockDim.x) >> 6;
    xform_body(h, Ws, Wn, b, yS, yN, gwave, nwaves, lane);
}

// ---------------- fused mean-aggregate + self + epilogue (R10, unchanged) ----------
// uint4 gathers (1 KB/wave-instr), deg-adaptive 16-edge rounds, masked slots
// read row 0 and contribute *0.0f (exact). 8 accumulators, 3 xor-shuffles
// each; lane (q,fq) writes feature fq*8+q.
__global__ __launch_bounds__(256) void k_aggf(const char* __restrict__ yN,
        const float* __restrict__ yS,
        const int* __restrict__ cnt, const int* __restrict__ csr,
        float* __restrict__ out, int relu) {
    int node = __builtin_amdgcn_readfirstlane((blockIdx.x * blockDim.x + threadIdx.x) >> 6);
    int lane = threadIdx.x & 63;
    int q = lane >> 3;          // edge sub-slot 0..7
    int fq = lane & 7;          // uint4 slot within the 128 B row
    int deg = cnt[node];
    const int* bucket = csr + (node << 6);
    unsigned foff = (unsigned)fq * 16u;

    float s0 = 0.f, s1 = 0.f, s2 = 0.f, s3 = 0.f;
    float s4 = 0.f, s5 = 0.f, s6 = 0.f, s7 = 0.f;

#define ROUND16(E0)                                                         \
    {                                                                       \
        int i0 = (E0) + q, i1 = i0 + 8;                                     \
        int b0 = bucket[i0], b1 = bucket[i1];                               \
        unsigned a0 = (i0 < deg) ? ((unsigned)b0 << 7) : 0u;                \
        unsigned a1 = (i1 < deg) ? ((unsigned)b1 << 7) : 0u;                \
        float m0 = (i0 < deg) ? 1.f : 0.f;                                  \
        float m1 = (i1 < deg) ? 1.f : 0.f;                                  \
        uint4 u0 = *(const uint4*)(yN + a0 + foff);                         \
        uint4 u1 = *(const uint4*)(yN + a1 + foff);                         \
        s0 = fmaf(m0, bflo(u0.x), s0); s0 = fmaf(m1, bflo(u1.x), s0);       \
        s1 = fmaf(m0, bfhi(u0.x), s1); s1 = fmaf(m1, bfhi(u1.x), s1);       \
        s2 = fmaf(m0, bflo(u0.y), s2); s2 = fmaf(m1, bflo(u1.y), s2);       \
        s3 = fmaf(m0, bfhi(u0.y), s3); s3 = fmaf(m1, bfhi(u1.y), s3);       \
        s4 = fmaf(m0, bflo(u0.z), s4); s4 = fmaf(m1, bflo(u1.z), s4);       \
        s5 = fmaf(m0, bfhi(u0.z), s5); s5 = fmaf(m1, bfhi(u1.z), s5);       \
        s6 = fmaf(m0, bflo(u0.w), s6); s6 = fmaf(m1, bflo(u1.w), s6);       \
        s7 = fmaf(m0, bfhi(u0.w), s7); s7 = fmaf(m1, bfhi(u1.w), s7);       \
    }

    ROUND16(0)                          // deg<=16: 53% of nodes stop here
    if (deg > 16) ROUND16(16)           // ~44%
    if (deg > 32) {                     // ~3%
        ROUND16(32)
        if (deg > 48) ROUND16(48)       // ~1e-4
    }
#undef ROUND16

    s0 += __shfl_xor(s0, 8, 64); s0 += __shfl_xor(s0, 16, 64); s0 += __shfl_xor(s0, 32, 64);
    s1 += __shfl_xor(s1, 8, 64); s1 += __shfl_xor(s1, 16, 64); s1 += __shfl_xor(s1, 32, 64);
    s2 += __shfl_xor(s2, 8, 64); s2 += __shfl_xor(s2, 16, 64); s2 += __shfl_xor(s2, 32, 64);
    s3 += __shfl_xor(s3, 8, 64); s3 += __shfl_xor(s3, 16, 64); s3 += __shfl_xor(s3, 32, 64);
    s4 += __shfl_xor(s4, 8, 64); s4 += __shfl_xor(s4, 16, 64); s4 += __shfl_xor(s4, 32, 64);
    s5 += __shfl_xor(s5, 8, 64); s5 += __shfl_xor(s5, 16, 64); s5 += __shfl_xor(s5, 32, 64);
    s6 += __shfl_xor(s6, 8, 64); s6 += __shfl_xor(s6, 16, 64); s6 += __shfl_xor(s6, 32, 64);
    s7 += __shfl_xor(s7, 8, 64); s7 += __shfl_xor(s7, 16, 64); s7 += __shfl_xor(s7, 32, 64);

    float sv = (q == 0) ? s0 : (q == 1) ? s1 : (q == 2) ? s2 : (q == 3) ? s3
             : (q == 4) ? s4 : (q == 5) ? s5 : (q == 6) ? s6 : s7;
    int f = fq * 8 + q;                      // feature this lane writes
    float self = yS[(size_t)node * D + f];
    float inv = 1.0f / fmaxf((float)deg, 1.0f);
    float acc = self + sv * inv;
    if (relu) acc = fmaxf(acc, 0.f);
    out[(size_t)node * D + f] = acc;
}

extern "C" void kernel_launch(void* const* d_in, const int* in_sizes, int n_in,
                              void* d_out, int out_size, void* d_ws, size_t ws_size,
                              hipStream_t stream) {
    const float* x   = (const float*)d_in[0];
    const int*   src = (const int*)d_in[1];
    const int*   dst = (const int*)d_in[2];
    const float* Ws0 = (const float*)d_in[3];
    const float* Wn0 = (const float*)d_in[4];
    const float* b0  = (const float*)d_in[5];
    const float* Ws1 = (const float*)d_in[6];
    const float* Wn1 = (const float*)d_in[7];
    const float* b1  = (const float*)d_in[8];
    float* out = (float*)d_out;

    // workspace layout
    char* p = (char*)d_ws;
    float*          yS  = (float*)p;          p += (size_t)N_NODES * D * sizeof(float);
    unsigned short* yN  = (unsigned short*)p; p += (size_t)N_NODES * D * sizeof(unsigned short);
    int* cnt = (int*)p;                       p += (size_t)N_NODES * sizeof(int);
    int* csr = (int*)p;                       p += (size_t)N_NODES * BCAP * sizeof(int);

    const int aggBlocks = (N_NODES + 3) / 4;     // 12500: wave per node, exact

    // tiny cnt zero (200 KB), stream-ordered before the fused stage
    hipMemsetAsync(cnt, 0, (size_t)N_NODES * sizeof(int), stream);

    // stage 1: layer-0 transform ∥ single-pass CSR fill (co-scheduled)
    k_pre<<<2048, 256, 0, stream>>>(x, Ws0, Wn0, b0, yS, yN, src, dst, cnt, csr);

    // layer 0 aggregate -> h in d_out
    k_aggf<<<aggBlocks, 256, 0, stream>>>((const char*)yN, yS, cnt, csr, out, 1);

    // layer 1 transform + aggregate -> d_out
    k_xform<<<1024, 256, 0, stream>>>(out, Ws1, Wn1, b1, yS, yN);

    k_aggf<<<aggBlocks, 256, 0, stream>>>((const char*)yN, yS, cnt, csr, out, 0);
}

// Round 15
// 190.776 us; speedup vs baseline: 1.5531x; 1.0107x over previous
//
#include <hip/hip_runtime.h>

#define N_NODES 50000
#define N_EDGES 800000
#define D 64
#define BCAP 64        // bucket capacity; deg ~ Poisson(16), P(deg>=64) ~ 1e-19
#define PRE_BLOCKS 2048

// float -> bf16 (round-to-nearest-even), as raw ushort
__device__ __forceinline__ unsigned short f2bf(float f) {
    unsigned int u = __builtin_bit_cast(unsigned int, f);
    u += 0x7fffu + ((u >> 16) & 1u);
    return (unsigned short)(u >> 16);
}
__device__ __forceinline__ float bflo(unsigned int u) {
    return __builtin_bit_cast(float, u << 16);
}
__device__ __forceinline__ float bfhi(unsigned int u) {
    return __builtin_bit_cast(float, u & 0xffff0000u);
}

// ---------------- shared transform body: yS = h@Ws + b (fp32), yN = h@Wn (bf16) ----
// Wave-specialized (even gwave -> Ws/yS, odd -> Wn/yN). Lane = output column,
// W column held in 64 VGPRs — REQUIRES the enclosing kernel to allow >=100
// VGPR (__launch_bounds__(256,4)); R12/R14's plain (256) bound let the
// compiler cap at 40 VGPR and demote w[] to re-loads (k_pre 80 us mystery).
__device__ __forceinline__ void xform_body(const float* __restrict__ h,
        const float* __restrict__ Ws, const float* __restrict__ Wn,
        const float* __restrict__ b,
        float* __restrict__ yS, unsigned short* __restrict__ yN,
        int gwave, int nwaves, int lane) {
    int mat = gwave & 1;
    const float* W = mat ? Wn : Ws;

    float w[D];
#pragma unroll
    for (int k = 0; k < D; ++k) w[k] = W[k * D + lane];
    float bj = mat ? 0.f : b[lane];

    const int ngroups = (N_NODES + 3) / 4;   // 12500, exact
    for (int g = gwave >> 1; g < ngroups; g += (nwaves >> 1)) {
        const float* x0 = h + (size_t)(g * 4) * D;
        float a0 = bj, a1 = bj, a2 = bj, a3 = bj;
#pragma unroll
        for (int kq = 0; kq < 16; ++kq) {
            float4 v0 = *(const float4*)(x0 + 0 * D + kq * 4);
            float4 v1 = *(const float4*)(x0 + 1 * D + kq * 4);
            float4 v2 = *(const float4*)(x0 + 2 * D + kq * 4);
            float4 v3 = *(const float4*)(x0 + 3 * D + kq * 4);
            a0 = fmaf(v0.x, w[kq * 4 + 0], a0);
            a1 = fmaf(v1.x, w[kq * 4 + 0], a1);
            a2 = fmaf(v2.x, w[kq * 4 + 0], a2);
            a3 = fmaf(v3.x, w[kq * 4 + 0], a3);
            a0 = fmaf(v0.y, w[kq * 4 + 1], a0);
            a1 = fmaf(v1.y, w[kq * 4 + 1], a1);
            a2 = fmaf(v2.y, w[kq * 4 + 1], a2);
            a3 = fmaf(v3.y, w[kq * 4 + 1], a3);
            a0 = fmaf(v0.z, w[kq * 4 + 2], a0);
            a1 = fmaf(v1.z, w[kq * 4 + 2], a1);
            a2 = fmaf(v2.z, w[kq * 4 + 2], a2);
            a3 = fmaf(v3.z, w[kq * 4 + 2], a3);
            a0 = fmaf(v0.w, w[kq * 4 + 3], a0);
            a1 = fmaf(v1.w, w[kq * 4 + 3], a1);
            a2 = fmaf(v2.w, w[kq * 4 + 3], a2);
            a3 = fmaf(v3.w, w[kq * 4 + 3], a3);
        }
        size_t base = (size_t)(g * 4) * D + lane;
        if (mat) {
            yN[base + 0 * D] = f2bf(a0);
            yN[base + 1 * D] = f2bf(a1);
            yN[base + 2 * D] = f2bf(a2);
            yN[base + 3 * D] = f2bf(a3);
        } else {
            yS[base + 0 * D] = a0;
            yS[base + 1 * D] = a1;
            yS[base + 2 * D] = a2;
            yS[base + 3 * D] = a3;
        }
    }
}

// ---------------- stage 1: CSR fill (phase 1) + layer-0 transform (phase 2) ----------
// Block-interleaved instead of role-split: each of 2048 blocks fills its ~391
// contiguous edges (1-2 atomics/thread), then grid-strides xform groups. All
// 8192 waves co-resident; fill's atomic latency hides under other blocks' FMA
// (m114 co-scheduling). No XCD assumptions (R13's XCC_ID scheme: rejected).
__global__ __launch_bounds__(256, 4) void k_pre(const float* __restrict__ x,
        const float* __restrict__ Ws0, const float* __restrict__ Wn0,
        const float* __restrict__ b0,
        float* __restrict__ yS, unsigned short* __restrict__ yN,
        const int* __restrict__ src, const int* __restrict__ dst,
        int* __restrict__ cnt, int* __restrict__ csr) {
    // phase 1: bucket-CSR fill of this block's edge chunk
    const int per = (N_EDGES + PRE_BLOCKS - 1) / PRE_BLOCKS;   // 391
    int e0 = blockIdx.x * per;
    int e1 = e0 + per; if (e1 > N_EDGES) e1 = N_EDGES;
    for (int e = e0 + (int)threadIdx.x; e < e1; e += 256) {
        int d = dst[e];
        int p = atomicAdd(&cnt[d], 1);
        csr[(d << 6) + p] = src[e];
    }
    // phase 2: layer-0 transform (grid-stride over node groups)
    int lane = threadIdx.x & 63;
    int gwave = __builtin_amdgcn_readfirstlane(blockIdx.x * 4 + (int)(threadIdx.x >> 6));
    xform_body(x, Ws0, Wn0, b0, yS, yN, gwave, PRE_BLOCKS * 4, lane);
}

// ---------------- layer-1 transform (standalone) ----------------
__global__ __launch_bounds__(256, 4) void k_xform(const float* __restrict__ h,
        const float* __restrict__ Ws, const float* __restrict__ Wn,
        const float* __restrict__ b,
        float* __restrict__ yS, unsigned short* __restrict__ yN) {
    int lane = threadIdx.x & 63;
    int gwave = __builtin_amdgcn_readfirstlane((blockIdx.x * blockDim.x + threadIdx.x) >> 6);
    int nwaves = (gridDim.x * blockDim.x) >> 6;
    xform_body(h, Ws, Wn, b, yS, yN, gwave, nwaves, lane);
}

// ---------------- fused mean-aggregate + self + epilogue ----------------
// uint4 gathers (1 KB/wave-instr), deg-adaptive 16-edge rounds. (256,4) bound
// lets the 8-deep load pipeline actually live in registers (plain (256) capped
// VGPR at ~40 -> serialized loads; explains R7/R9/R10 flat results).
__global__ __launch_bounds__(256, 4) void k_aggf(const char* __restrict__ yN,
        const float* __restrict__ yS,
        const int* __restrict__ cnt, const int* __restrict__ csr,
        float* __restrict__ out, int relu) {
    int node = __builtin_amdgcn_readfirstlane((blockIdx.x * blockDim.x + threadIdx.x) >> 6);
    int lane = threadIdx.x & 63;
    int q = lane >> 3;          // edge sub-slot 0..7
    int fq = lane & 7;          // uint4 slot within the 128 B row
    int deg = cnt[node];
    const int* bucket = csr + (node << 6);
    unsigned foff = (unsigned)fq * 16u;

    float s0 = 0.f, s1 = 0.f, s2 = 0.f, s3 = 0.f;
    float s4 = 0.f, s5 = 0.f, s6 = 0.f, s7 = 0.f;

#define ROUND16(E0)                                                         \
    {                                                                       \
        int i0 = (E0) + q, i1 = i0 + 8;                                     \
        int b0 = bucket[i0], b1 = bucket[i1];                               \
        unsigned a0 = (i0 < deg) ? ((unsigned)b0 << 7) : 0u;                \
        unsigned a1 = (i1 < deg) ? ((unsigned)b1 << 7) : 0u;                \
        float m0 = (i0 < deg) ? 1.f : 0.f;                                  \
        float m1 = (i1 < deg) ? 1.f : 0.f;                                  \
        uint4 u0 = *(const uint4*)(yN + a0 + foff);                         \
        uint4 u1 = *(const uint4*)(yN + a1 + foff);                         \
        s0 = fmaf(m0, bflo(u0.x), s0); s0 = fmaf(m1, bflo(u1.x), s0);       \
        s1 = fmaf(m0, bfhi(u0.x), s1); s1 = fmaf(m1, bfhi(u1.x), s1);       \
        s2 = fmaf(m0, bflo(u0.y), s2); s2 = fmaf(m1, bflo(u1.y), s2);       \
        s3 = fmaf(m0, bfhi(u0.y), s3); s3 = fmaf(m1, bfhi(u1.y), s3);       \
        s4 = fmaf(m0, bflo(u0.z), s4); s4 = fmaf(m1, bflo(u1.z), s4);       \
        s5 = fmaf(m0, bfhi(u0.z), s5); s5 = fmaf(m1, bfhi(u1.z), s5);       \
        s6 = fmaf(m0, bflo(u0.w), s6); s6 = fmaf(m1, bflo(u1.w), s6);       \
        s7 = fmaf(m0, bfhi(u0.w), s7); s7 = fmaf(m1, bfhi(u1.w), s7);       \
    }

    ROUND16(0)                          // deg<=16: 53% of nodes stop here
    if (deg > 16) ROUND16(16)           // ~44%
    if (deg > 32) {                     // ~3%
        ROUND16(32)
        if (deg > 48) ROUND16(48)       // ~1e-4
    }
#undef ROUND16

    s0 += __shfl_xor(s0, 8, 64); s0 += __shfl_xor(s0, 16, 64); s0 += __shfl_xor(s0, 32, 64);
    s1 += __shfl_xor(s1, 8, 64); s1 += __shfl_xor(s1, 16, 64); s1 += __shfl_xor(s1, 32, 64);
    s2 += __shfl_xor(s2, 8, 64); s2 += __shfl_xor(s2, 16, 64); s2 += __shfl_xor(s2, 32, 64);
    s3 += __shfl_xor(s3, 8, 64); s3 += __shfl_xor(s3, 16, 64); s3 += __shfl_xor(s3, 32, 64);
    s4 += __shfl_xor(s4, 8, 64); s4 += __shfl_xor(s4, 16, 64); s4 += __shfl_xor(s4, 32, 64);
    s5 += __shfl_xor(s5, 8, 64); s5 += __shfl_xor(s5, 16, 64); s5 += __shfl_xor(s5, 32, 64);
    s6 += __shfl_xor(s6, 8, 64); s6 += __shfl_xor(s6, 16, 64); s6 += __shfl_xor(s6, 32, 64);
    s7 += __shfl_xor(s7, 8, 64); s7 += __shfl_xor(s7, 16, 64); s7 += __shfl_xor(s7, 32, 64);

    float sv = (q == 0) ? s0 : (q == 1) ? s1 : (q == 2) ? s2 : (q == 3) ? s3
             : (q == 4) ? s4 : (q == 5) ? s5 : (q == 6) ? s6 : s7;
    int f = fq * 8 + q;                      // feature this lane writes
    float self = yS[(size_t)node * D + f];
    float inv = 1.0f / fmaxf((float)deg, 1.0f);
    float acc = self + sv * inv;
    if (relu) acc = fmaxf(acc, 0.f);
    out[(size_t)node * D + f] = acc;
}

extern "C" void kernel_launch(void* const* d_in, const int* in_sizes, int n_in,
                              void* d_out, int out_size, void* d_ws, size_t ws_size,
                              hipStream_t stream) {
    const float* x   = (const float*)d_in[0];
    const int*   src = (const int*)d_in[1];
    const int*   dst = (const int*)d_in[2];
    const float* Ws0 = (const float*)d_in[3];
    const float* Wn0 = (const float*)d_in[4];
    const float* b0  = (const float*)d_in[5];
    const float* Ws1 = (const float*)d_in[6];
    const float* Wn1 = (const float*)d_in[7];
    const float* b1  = (const float*)d_in[8];
    float* out = (float*)d_out;

    // workspace layout
    char* p = (char*)d_ws;
    float*          yS  = (float*)p;          p += (size_t)N_NODES * D * sizeof(float);
    unsigned short* yN  = (unsigned short*)p; p += (size_t)N_NODES * D * sizeof(unsigned short);
    int* cnt = (int*)p;                       p += (size_t)N_NODES * sizeof(int);
    int* csr = (int*)p;                       p += (size_t)N_NODES * BCAP * sizeof(int);

    const int aggBlocks = (N_NODES + 3) / 4;     // 12500: wave per node, exact

    // tiny cnt zero (200 KB), stream-ordered before the fused stage
    hipMemsetAsync(cnt, 0, (size_t)N_NODES * sizeof(int), stream);

    // stage 1: CSR fill + layer-0 transform (block-interleaved phases)
    k_pre<<<PRE_BLOCKS, 256, 0, stream>>>(x, Ws0, Wn0, b0, yS, yN, src, dst, cnt, csr);

    // layer 0 aggregate -> h in d_out
    k_aggf<<<aggBlocks, 256, 0, stream>>>((const char*)yN, yS, cnt, csr, out, 1);

    // layer 1 transform + aggregate -> d_out
    k_xform<<<1024, 256, 0, stream>>>(out, Ws1, Wn1, b1, yS, yN);
    k_aggf<<<aggBlocks, 256, 0, stream>>>((const char*)yN, yS, cnt, csr, out, 0);
}